// Round 5
// baseline (512.444 us; speedup 1.0000x reference)
//
#include <hip/hip_runtime.h>

#define MDIM 2048   // B
#define KD   2560   // HEAD
#define NHID 2048   // N_HID
#define INF  512
#define NTOT 10240  // 5*NHID
#define NS   40     // K-steps of 64

typedef __attribute__((ext_vector_type(16))) float f32x16;
typedef __attribute__((ext_vector_type(8))) short short8;
typedef __attribute__((ext_vector_type(8))) unsigned short ushort8v;
typedef __attribute__((ext_vector_type(4))) unsigned short ushort4v;

#define AS1 __attribute__((address_space(1)))
#define AS3 __attribute__((address_space(3)))

__device__ __forceinline__ unsigned short f2bf(float f) {
    unsigned u = __float_as_uint(f);
    u += 0x7fffu + ((u >> 16) & 1u);
    return (unsigned short)(u >> 16);
}
__device__ __forceinline__ float bf2f(unsigned short s) {
    return __uint_as_float(((unsigned)s) << 16);
}

// ---------------- prep: xc = concat(x, hidden) -> bf16 [MDIM][KD] ----------------
__global__ void prep_xc(const float* __restrict__ x, const float* __restrict__ h,
                        unsigned short* __restrict__ xc) {
    int idx = blockIdx.x * 256 + threadIdx.x;
    int e = idx * 8;
    int b = e / KD;
    int c = e - b * KD;
    const float* src = (c < INF) ? (x + (size_t)b * INF + c)
                                 : (h + (size_t)b * NHID + (c - INF));
    float4 v0 = *(const float4*)src;
    float4 v1 = *(const float4*)(src + 4);
    ushort8v o;
    o[0] = f2bf(v0.x); o[1] = f2bf(v0.y); o[2] = f2bf(v0.z); o[3] = f2bf(v0.w);
    o[4] = f2bf(v1.x); o[5] = f2bf(v1.y); o[6] = f2bf(v1.z); o[7] = f2bf(v1.w);
    *(ushort8v*)(xc + e) = o;
}

// ---------------- prep: Wm[k] = W_k * mask -> bf16, 5 planes = [NTOT][KD] ----------------
// mask cols >= INF are all 1.0 by construction -> only fetch mask for cols < INF.
__global__ void prep_wm(const float* __restrict__ Wg, const float* __restrict__ Wh,
                        const float* __restrict__ Wfg, const float* __restrict__ Wfh,
                        const float* __restrict__ Wp, const float* __restrict__ mask,
                        unsigned short* __restrict__ Wm) {
    int idx = blockIdx.x * 256 + threadIdx.x;
    size_t e = (size_t)idx * 4;
    const size_t PL = (size_t)NHID * KD;
    int col = (int)(e % KD);
    float4 m;
    if (col < INF) m = *(const float4*)(mask + e);
    else           m = make_float4(1.f, 1.f, 1.f, 1.f);
    const float* Ws[5] = {Wg, Wh, Wfg, Wfh, Wp};
    #pragma unroll
    for (int k = 0; k < 5; ++k) {
        float4 w = *(const float4*)(Ws[k] + e);
        ushort4v o;
        o[0] = f2bf(w.x * m.x); o[1] = f2bf(w.y * m.y);
        o[2] = f2bf(w.z * m.z); o[3] = f2bf(w.w * m.w);
        *(ushort4v*)(Wm + k * PL + e) = o;
    }
}

// ---------------- GEMM: C[2048][10240] = A (2048xK) . B^T (10240xK) ----------------
// 32x32x16 MFMA. BM=256 BN=320 BK=64. 4 waves (2M x 2N), per-wave 128x160 =
// 4x5 fragments -> 9 ds_read_b128 per 20 MFMA (LDS read bytes/MFMA cut 1.55x
// vs 8-wave 2x5: LDS BW was the measured bottleneck, MfmaUtil 41%).
// 1 wave/SIMD, 512-VGPR budget (acc = 320 f32). grid 32x8 = 256 = 1 block/CU.
// Single barrier per K-step; staging for kt+1 -> opposite buffer, drained by
// vmcnt(0) at the boundary after ~2600 cyc in flight. XOR swizzle slot^=(row&7).
#define MFMA32(d, va, vb) d = __builtin_amdgcn_mfma_f32_32x32x16_bf16(va, vb, d, 0, 0, 0)

__global__ __launch_bounds__(256, 1) void gemm32(
    const unsigned short* __restrict__ A,
    const unsigned short* __restrict__ B,
    unsigned short* __restrict__ C) {
    __shared__ unsigned short lsA[2][256 * 64];   // 64 KB
    __shared__ unsigned short lsB[2][320 * 64];   // 80 KB

    const int tid  = threadIdx.x;
    const int lane = tid & 63;
    const int w    = tid >> 6;       // 0..3
    const int wm   = w >> 1;         // 0..1  (M waves)
    const int wn   = w & 1;          // 0..1  (N waves)
    const int l31  = lane & 31;
    const int hi   = lane >> 5;      // 0..1
    const int l7   = lane & 7;
    const int m0   = blockIdx.y * 256;
    const int n0   = blockIdx.x * 320;

    const unsigned short* gA = A + (size_t)m0 * KD;
    const unsigned short* gB = B + (size_t)n0 * KD;
    // staging: per-lane source offset, 8 rows x 8 slots, slot pre-swizzled by row&7
    const int soff = (lane >> 3) * KD + (((lane & 7) ^ (lane >> 3)) << 3);
    const int arS = w * 64;   // staging A rows [arS, arS+64), 8 loads
    const int brS = w * 80;   // staging B rows [brS, brS+80), 10 loads

#define SA(j, t, b) __builtin_amdgcn_global_load_lds( \
        (const AS1 unsigned int*)(gA + (size_t)(arS + 8 * (j)) * KD + (t) * 64 + soff), \
        (AS3 unsigned int*)(&lsA[b][(arS + 8 * (j)) * 64]), 16, 0, 0)
#define SB(j, t, b) __builtin_amdgcn_global_load_lds( \
        (const AS1 unsigned int*)(gB + (size_t)(brS + 8 * (j)) * KD + (t) * 64 + soff), \
        (AS3 unsigned int*)(&lsB[b][(brS + 8 * (j)) * 64]), 16, 0, 0)
#define STAGE(t, b) do { \
        SA(0, t, b); SA(1, t, b); SA(2, t, b); SA(3, t, b); \
        SA(4, t, b); SA(5, t, b); SA(6, t, b); SA(7, t, b); \
        SB(0, t, b); SB(1, t, b); SB(2, t, b); SB(3, t, b); SB(4, t, b); \
        SB(5, t, b); SB(6, t, b); SB(7, t, b); SB(8, t, b); SB(9, t, b); \
    } while (0)

    // fragment read bases (ushort index): row*64 + swizzled-slot*8
    const int arow = wm * 128 + l31;   // + 32*m, m=0..3
    const int brow = wn * 160 + l31;   // + 32*n, n=0..4

    f32x16 acc[4][5] = {};

    // prologue: stage kt=0 into buf 0
    STAGE(0, 0);
    asm volatile("s_waitcnt vmcnt(0)" ::: "memory");
    __builtin_amdgcn_s_barrier();

    for (int kt = 0; kt < NS; ++kt) {
        const int bc = kt & 1, bo = bc ^ 1;
        if (kt < NS - 1) STAGE(kt + 1, bo);
        // 4 k-subtiles of 16; reads for s+1 issue in the MFMA shadow of s (ILP)
        #pragma unroll
        for (int s = 0; s < 4; ++s) {
            const int cs = (((2 * s + hi) ^ l7) << 3);
            short8 av[4], bv[5];
            #pragma unroll
            for (int m = 0; m < 4; ++m)
                av[m] = *(const short8*)&lsA[bc][(arow + 32 * m) * 64 + cs];
            #pragma unroll
            for (int n = 0; n < 5; ++n)
                bv[n] = *(const short8*)&lsB[bc][(brow + 32 * n) * 64 + cs];
            #pragma unroll
            for (int m = 0; m < 4; ++m)
                #pragma unroll
                for (int n = 0; n < 5; ++n)
                    MFMA32(acc[m][n], av[m], bv[n]);
        }
        // boundary: own staging drained (in flight the whole step), sync, flip
        asm volatile("s_waitcnt vmcnt(0)" ::: "memory");
        __builtin_amdgcn_s_barrier();
    }

    // C/D layout (32x32): col = lane&31, row = (reg&3) + 8*(reg>>2) + 4*hi
    #pragma unroll
    for (int m = 0; m < 4; ++m) {
        #pragma unroll
        for (int n = 0; n < 5; ++n) {
            int col = n0 + wn * 160 + n * 32 + l31;
            #pragma unroll
            for (int q = 0; q < 4; ++q) {
                int row = m0 + wm * 128 + m * 32 + q * 8 + 4 * hi;
                #pragma unroll
                for (int t = 0; t < 4; ++t)
                    C[(size_t)(row + t) * NTOT + col] = f2bf(acc[m][n][q * 4 + t]);
            }
        }
    }
#undef SA
#undef SB
#undef STAGE
}

// ---------------- epilogue: activations + mix -> y_pred, new_hidden (f32) ----------------
__global__ void epilogue(const unsigned short* __restrict__ C,
                         const float* __restrict__ bg, const float* __restrict__ bh,
                         const float* __restrict__ bfg, const float* __restrict__ bfh,
                         const float* __restrict__ bp,
                         float* __restrict__ out) {
    int idx = blockIdx.x * 256 + threadIdx.x;
    size_t e = (size_t)idx * 8;
    int b = (int)(e >> 11);
    int o = (int)(e & (NHID - 1));
    const size_t PL = (size_t)MDIM * NHID;
    const unsigned short* row = C + (size_t)b * NTOT + o;

    ushort8v vg  = *(const ushort8v*)(row + 0 * NHID);
    ushort8v vh  = *(const ushort8v*)(row + 1 * NHID);
    ushort8v vfg = *(const ushort8v*)(row + 2 * NHID);
    ushort8v vfh = *(const ushort8v*)(row + 3 * NHID);
    ushort8v vp  = *(const ushort8v*)(row + 4 * NHID);

    float bgv[8], bhv[8], bfgv[8], bfhv[8], bpv[8];
    *(float4*)bgv  = *(const float4*)(bg + o);  *(float4*)(bgv + 4)  = *(const float4*)(bg + o + 4);
    *(float4*)bhv  = *(const float4*)(bh + o);  *(float4*)(bhv + 4)  = *(const float4*)(bh + o + 4);
    *(float4*)bfgv = *(const float4*)(bfg + o); *(float4*)(bfgv + 4) = *(const float4*)(bfg + o + 4);
    *(float4*)bfhv = *(const float4*)(bfh + o); *(float4*)(bfhv + 4) = *(const float4*)(bfh + o + 4);
    *(float4*)bpv  = *(const float4*)(bp + o);  *(float4*)(bpv + 4)  = *(const float4*)(bp + o + 4);

    float yv[8], nhv[8];
    #pragma unroll
    for (int j = 0; j < 8; ++j) {
        float g    = tanhf(bf2f(vg[j]) + bgv[j]);
        float hh   = tanhf(bf2f(vh[j]) + bhv[j]);
        float s    = bf2f(vfg[j]) + bfgv[j] + bf2f(vfh[j]) + bfhv[j];
        float gate = 1.0f / (1.0f + __expf(-s));
        float nh   = g * (1.0f - gate) + gate * hh;
        nhv[j] = nh;
        yv[j]  = bf2f(vp[j]) + bpv[j] + nh;
    }
    *(float4*)(out + e)          = *(float4*)yv;
    *(float4*)(out + e + 4)      = *(float4*)(yv + 4);
    *(float4*)(out + PL + e)     = *(float4*)nhv;
    *(float4*)(out + PL + e + 4) = *(float4*)(nhv + 4);
}

extern "C" void kernel_launch(void* const* d_in, const int* in_sizes, int n_in,
                              void* d_out, int out_size, void* d_ws, size_t ws_size,
                              hipStream_t stream) {
    const float* x      = (const float*)d_in[0];
    const float* hidden = (const float*)d_in[1];
    const float* mask   = (const float*)d_in[2];
    const float* Wg     = (const float*)d_in[3];
    const float* bg     = (const float*)d_in[4];
    const float* Wh     = (const float*)d_in[5];
    const float* bh     = (const float*)d_in[6];
    const float* Wfg    = (const float*)d_in[7];
    const float* bfg    = (const float*)d_in[8];
    const float* Wfh    = (const float*)d_in[9];
    const float* bfh    = (const float*)d_in[10];
    const float* Wp     = (const float*)d_in[11];
    const float* bp     = (const float*)d_in[12];
    float* out = (float*)d_out;

    const size_t need = (size_t)MDIM * KD * 2 + (size_t)NTOT * KD * 2
                      + (size_t)MDIM * NTOT * 2;
    if (ws_size < need) return;

    unsigned short* xc = (unsigned short*)d_ws;
    unsigned short* Wm = xc + (size_t)MDIM * KD;
    unsigned short* C  = Wm + (size_t)NTOT * KD;

    prep_xc<<<MDIM * KD / 8 / 256, 256, 0, stream>>>(x, hidden, xc);
    prep_wm<<<NHID * KD / 4 / 256, 256, 0, stream>>>(Wg, Wh, Wfg, Wfh, Wp, mask, Wm);
    dim3 grid(NTOT / 320, MDIM / 256);
    gemm32<<<grid, 256, 0, stream>>>(xc, Wm, C);
    epilogue<<<MDIM * NHID / 8 / 256, 256, 0, stream>>>(C, bg, bh, bfg, bfh, bp, out);
}

// Round 6
// 146.740 us; speedup vs baseline: 3.4922x; 3.4922x over previous
//
#include <hip/hip_runtime.h>

#define MDIM 2048   // B
#define KD   2560   // HEAD
#define NHID 2048   // N_HID
#define INF  512
#define NTOT 10240  // 5*NHID
#define NS   40     // K-steps of 64

typedef __attribute__((ext_vector_type(4))) float f32x4;
typedef __attribute__((ext_vector_type(8))) short short8;
typedef __attribute__((ext_vector_type(8))) unsigned short ushort8v;
typedef __attribute__((ext_vector_type(4))) unsigned short ushort4v;

#define AS1 __attribute__((address_space(1)))
#define AS3 __attribute__((address_space(3)))

__device__ __forceinline__ unsigned short f2bf(float f) {
    unsigned u = __float_as_uint(f);
    u += 0x7fffu + ((u >> 16) & 1u);
    return (unsigned short)(u >> 16);
}
__device__ __forceinline__ float bf2f(unsigned short s) {
    return __uint_as_float(((unsigned)s) << 16);
}

// ---------------- prep: xc = concat(x, hidden) -> bf16 [MDIM][KD] ----------------
__global__ void prep_xc(const float* __restrict__ x, const float* __restrict__ h,
                        unsigned short* __restrict__ xc) {
    int idx = blockIdx.x * 256 + threadIdx.x;
    int e = idx * 8;
    int b = e / KD;
    int c = e - b * KD;
    const float* src = (c < INF) ? (x + (size_t)b * INF + c)
                                 : (h + (size_t)b * NHID + (c - INF));
    float4 v0 = *(const float4*)src;
    float4 v1 = *(const float4*)(src + 4);
    ushort8v o;
    o[0] = f2bf(v0.x); o[1] = f2bf(v0.y); o[2] = f2bf(v0.z); o[3] = f2bf(v0.w);
    o[4] = f2bf(v1.x); o[5] = f2bf(v1.y); o[6] = f2bf(v1.z); o[7] = f2bf(v1.w);
    *(ushort8v*)(xc + e) = o;
}

// ---------------- prep: Wm[k] = W_k * mask -> bf16, 5 planes = [NTOT][KD] ----------------
// mask cols >= INF are all 1.0 by construction -> only fetch mask for cols < INF.
__global__ void prep_wm(const float* __restrict__ Wg, const float* __restrict__ Wh,
                        const float* __restrict__ Wfg, const float* __restrict__ Wfh,
                        const float* __restrict__ Wp, const float* __restrict__ mask,
                        unsigned short* __restrict__ Wm) {
    int idx = blockIdx.x * 256 + threadIdx.x;
    size_t e = (size_t)idx * 4;
    const size_t PL = (size_t)NHID * KD;
    int col = (int)(e % KD);
    float4 m;
    if (col < INF) m = *(const float4*)(mask + e);
    else           m = make_float4(1.f, 1.f, 1.f, 1.f);
    const float* Ws[5] = {Wg, Wh, Wfg, Wfh, Wp};
    #pragma unroll
    for (int k = 0; k < 5; ++k) {
        float4 w = *(const float4*)(Ws[k] + e);
        ushort4v o;
        o[0] = f2bf(w.x * m.x); o[1] = f2bf(w.y * m.y);
        o[2] = f2bf(w.z * m.z); o[3] = f2bf(w.w * m.w);
        *(ushort4v*)(Wm + k * PL + e) = o;
    }
}

// ---------------- 4-phase GEMM: C[2048][10240] = A (2048xK) . B^T (10240xK) ----------------
// m201-style phase schedule. 16x16x32 MFMA. BM=256 BN=320 BK=64, 8 waves
// (2M x 4N), per-wave 128x80 = 8x5 frags, acc 160 f32 (AGPR). grid 256 = 1/CU.
// 4 phases per K-tile, split (M-half x K-half); each phase:
//   {ds_read frags, issue 3 staging loads for kt+1 -> other buffer,
//    s_barrier, sched_barrier, setprio(1), 20 MFMA, setprio(0), s_barrier}
// vmcnt(0) once per K-tile at end of P3 (own staged loads >=1 phase old).
// Register budget: 18 live frag short8 = 72 VGPR + 160 acc + addr ~= 230 < 256.
// XOR swizzle slot^=(row&7) via pre-swizzled global source (round-2-verified,
// 0 bank conflicts with this 16-row read pattern).
#define MFMA16(d, va, vb) d = __builtin_amdgcn_mfma_f32_16x16x32_bf16(va, vb, d, 0, 0, 0)

__global__ __launch_bounds__(512, 2) void gemm4p(
    const unsigned short* __restrict__ A,
    const unsigned short* __restrict__ B,
    unsigned short* __restrict__ C) {
    __shared__ unsigned short lsA[2][256 * 64];   // 64 KB
    __shared__ unsigned short lsB[2][320 * 64];   // 80 KB

    const int tid  = threadIdx.x;
    const int lane = tid & 63;
    const int w    = tid >> 6;       // 0..7
    const int wm   = w >> 2;         // 0..1  (M waves)
    const int wn   = w & 3;          // 0..3  (N waves)
    const int lr   = lane & 15;
    const int kq   = lane >> 4;      // 0..3
    const int l7   = lane & 7;
    const int m0   = blockIdx.y * 256;
    const int n0   = blockIdx.x * 320;

    const unsigned short* gA = A + (size_t)m0 * KD;
    const unsigned short* gB = B + (size_t)n0 * KD;
    // staging: per-lane source offset, 8 rows x 8 slots, slot pre-swizzled by row&7
    const int soff = (lane >> 3) * KD + (((lane & 7) ^ (lane >> 3)) << 3);
    const int ar0 = (w >> 2) * 128 + (w & 3) * 8;  // + 32*j, j=0..3
    const int br0 = (w >> 1) * 80 + (w & 1) * 8;   // + 16*j, j=0..4

#define SA(j, t, b) __builtin_amdgcn_global_load_lds( \
        (const AS1 unsigned int*)(gA + (size_t)(ar0 + 32 * (j)) * KD + (t) * 64 + soff), \
        (AS3 unsigned int*)(&lsA[b][(ar0 + 32 * (j)) * 64]), 16, 0, 0)
#define SB(j, t, b) __builtin_amdgcn_global_load_lds( \
        (const AS1 unsigned int*)(gB + (size_t)(br0 + 16 * (j)) * KD + (t) * 64 + soff), \
        (AS3 unsigned int*)(&lsB[b][(br0 + 16 * (j)) * 64]), 16, 0, 0)

    // swizzled ds_read col offsets (ushorts) for K-half 0/1
    const int c0 = ((0 + kq) ^ l7) << 3;
    const int c1 = ((4 + kq) ^ l7) << 3;
    const int arow = wm * 128 + lr;   // + 16*m, m=0..7
    const int brow = wn * 80 + lr;    // + 16*n, n=0..4

#define LDA(b, m, cs) (*(const short8*)&lsA[b][(arow + 16 * (m)) * 64 + (cs)])
#define LDB(b, n, cs) (*(const short8*)&lsB[b][(brow + 16 * (n)) * 64 + (cs)])

#define PBAR() do { __builtin_amdgcn_s_barrier(); \
                    __builtin_amdgcn_sched_barrier(0); } while (0)

    f32x4 acc[8][5] = {};

    // prologue: stage kt=0 into buf 0
    SA(0, 0, 0); SA(1, 0, 0); SA(2, 0, 0); SA(3, 0, 0);
    SB(0, 0, 0); SB(1, 0, 0); SB(2, 0, 0); SB(3, 0, 0); SB(4, 0, 0);
    asm volatile("s_waitcnt vmcnt(0)" ::: "memory");
    __builtin_amdgcn_s_barrier();

    for (int kt = 0; kt < NS; ++kt) {
        const int bc = kt & 1, bo = bc ^ 1;
        const bool st = (kt + 1 < NS);
        short8 aL[4], aH[4], b0[5], b1[5];

        // ---- P0: M 0-3, K-half 0 ----
        #pragma unroll
        for (int m = 0; m < 4; ++m) aL[m] = LDA(bc, m, c0);
        #pragma unroll
        for (int n = 0; n < 5; ++n) b0[n] = LDB(bc, n, c0);
        if (st) { SA(0, kt + 1, bo); SA(1, kt + 1, bo); SA(2, kt + 1, bo); }
        PBAR();
        __builtin_amdgcn_s_setprio(1);
        #pragma unroll
        for (int m = 0; m < 4; ++m)
            #pragma unroll
            for (int n = 0; n < 5; ++n) MFMA16(acc[m][n], aL[m], b0[n]);
        __builtin_amdgcn_s_setprio(0);
        PBAR();

        // ---- P1: M 0-3, K-half 1 ----
        #pragma unroll
        for (int m = 0; m < 4; ++m) aL[m] = LDA(bc, m, c1);
        #pragma unroll
        for (int n = 0; n < 5; ++n) b1[n] = LDB(bc, n, c1);
        if (st) { SA(3, kt + 1, bo); SB(0, kt + 1, bo); SB(1, kt + 1, bo); }
        PBAR();
        __builtin_amdgcn_s_setprio(1);
        #pragma unroll
        for (int m = 0; m < 4; ++m)
            #pragma unroll
            for (int n = 0; n < 5; ++n) MFMA16(acc[m][n], aL[m], b1[n]);
        __builtin_amdgcn_s_setprio(0);
        PBAR();

        // ---- P2: M 4-7, K-half 0 (b0 held live) ----
        #pragma unroll
        for (int m = 0; m < 4; ++m) aH[m] = LDA(bc, 4 + m, c0);
        if (st) { SB(2, kt + 1, bo); SB(3, kt + 1, bo); SB(4, kt + 1, bo); }
        PBAR();
        __builtin_amdgcn_s_setprio(1);
        #pragma unroll
        for (int m = 0; m < 4; ++m)
            #pragma unroll
            for (int n = 0; n < 5; ++n) MFMA16(acc[4 + m][n], aH[m], b0[n]);
        __builtin_amdgcn_s_setprio(0);
        PBAR();

        // ---- P3: M 4-7, K-half 1 (b1 held live) ----
        #pragma unroll
        for (int m = 0; m < 4; ++m) aH[m] = LDA(bc, 4 + m, c1);
        PBAR();
        __builtin_amdgcn_s_setprio(1);
        #pragma unroll
        for (int m = 0; m < 4; ++m)
            #pragma unroll
            for (int n = 0; n < 5; ++n) MFMA16(acc[4 + m][n], aH[m], b1[n]);
        __builtin_amdgcn_s_setprio(0);
        // flip gate: own staged loads for kt+1 are >=1 phase old -> near-free
        asm volatile("s_waitcnt vmcnt(0)" ::: "memory");
        __builtin_amdgcn_s_barrier();
    }

    // C/D layout (16x16): col = lane&15, row = (lane>>4)*4 + reg
    #pragma unroll
    for (int m = 0; m < 8; ++m) {
        int row = m0 + wm * 128 + m * 16 + kq * 4;
        #pragma unroll
        for (int n = 0; n < 5; ++n) {
            int col = n0 + wn * 80 + n * 16 + lr;
            #pragma unroll
            for (int j = 0; j < 4; ++j)
                C[(size_t)(row + j) * NTOT + col] = f2bf(acc[m][n][j]);
        }
    }
#undef SA
#undef SB
#undef LDA
#undef LDB
#undef PBAR
}

// ---------------- epilogue: activations + mix -> y_pred, new_hidden (f32) ----------------
__global__ void epilogue(const unsigned short* __restrict__ C,
                         const float* __restrict__ bg, const float* __restrict__ bh,
                         const float* __restrict__ bfg, const float* __restrict__ bfh,
                         const float* __restrict__ bp,
                         float* __restrict__ out) {
    int idx = blockIdx.x * 256 + threadIdx.x;
    size_t e = (size_t)idx * 8;
    int b = (int)(e >> 11);
    int o = (int)(e & (NHID - 1));
    const size_t PL = (size_t)MDIM * NHID;
    const unsigned short* row = C + (size_t)b * NTOT + o;

    ushort8v vg  = *(const ushort8v*)(row + 0 * NHID);
    ushort8v vh  = *(const ushort8v*)(row + 1 * NHID);
    ushort8v vfg = *(const ushort8v*)(row + 2 * NHID);
    ushort8v vfh = *(const ushort8v*)(row + 3 * NHID);
    ushort8v vp  = *(const ushort8v*)(row + 4 * NHID);

    float bgv[8], bhv[8], bfgv[8], bfhv[8], bpv[8];
    *(float4*)bgv  = *(const float4*)(bg + o);  *(float4*)(bgv + 4)  = *(const float4*)(bg + o + 4);
    *(float4*)bhv  = *(const float4*)(bh + o);  *(float4*)(bhv + 4)  = *(const float4*)(bh + o + 4);
    *(float4*)bfgv = *(const float4*)(bfg + o); *(float4*)(bfgv + 4) = *(const float4*)(bfg + o + 4);
    *(float4*)bfhv = *(const float4*)(bfh + o); *(float4*)(bfhv + 4) = *(const float4*)(bfh + o + 4);
    *(float4*)bpv  = *(const float4*)(bp + o);  *(float4*)(bpv + 4)  = *(const float4*)(bp + o + 4);

    float yv[8], nhv[8];
    #pragma unroll
    for (int j = 0; j < 8; ++j) {
        float g    = tanhf(bf2f(vg[j]) + bgv[j]);
        float hh   = tanhf(bf2f(vh[j]) + bhv[j]);
        float s    = bf2f(vfg[j]) + bfgv[j] + bf2f(vfh[j]) + bfhv[j];
        float gate = 1.0f / (1.0f + __expf(-s));
        float nh   = g * (1.0f - gate) + gate * hh;
        nhv[j] = nh;
        yv[j]  = bf2f(vp[j]) + bpv[j] + nh;
    }
    *(float4*)(out + e)          = *(float4*)yv;
    *(float4*)(out + e + 4)      = *(float4*)(yv + 4);
    *(float4*)(out + PL + e)     = *(float4*)nhv;
    *(float4*)(out + PL + e + 4) = *(float4*)(nhv + 4);
}

extern "C" void kernel_launch(void* const* d_in, const int* in_sizes, int n_in,
                              void* d_out, int out_size, void* d_ws, size_t ws_size,
                              hipStream_t stream) {
    const float* x      = (const float*)d_in[0];
    const float* hidden = (const float*)d_in[1];
    const float* mask   = (const float*)d_in[2];
    const float* Wg     = (const float*)d_in[3];
    const float* bg     = (const float*)d_in[4];
    const float* Wh     = (const float*)d_in[5];
    const float* bh     = (const float*)d_in[6];
    const float* Wfg    = (const float*)d_in[7];
    const float* bfg    = (const float*)d_in[8];
    const float* Wfh    = (const float*)d_in[9];
    const float* bfh    = (const float*)d_in[10];
    const float* Wp     = (const float*)d_in[11];
    const float* bp     = (const float*)d_in[12];
    float* out = (float*)d_out;

    const size_t need = (size_t)MDIM * KD * 2 + (size_t)NTOT * KD * 2
                      + (size_t)MDIM * NTOT * 2;
    if (ws_size < need) return;

    unsigned short* xc = (unsigned short*)d_ws;
    unsigned short* Wm = xc + (size_t)MDIM * KD;
    unsigned short* C  = Wm + (size_t)NTOT * KD;

    prep_xc<<<MDIM * KD / 8 / 256, 256, 0, stream>>>(x, hidden, xc);
    prep_wm<<<NHID * KD / 4 / 256, 256, 0, stream>>>(Wg, Wh, Wfg, Wfh, Wp, mask, Wm);
    dim3 grid(NTOT / 320, MDIM / 256);
    gemm4p<<<grid, 512, 0, stream>>>(xc, Wm, C);
    epilogue<<<MDIM * NHID / 8 / 256, 256, 0, stream>>>(C, bg, bh, bfg, bfh, bp, out);
}

// Round 7
// 139.118 us; speedup vs baseline: 3.6835x; 1.0548x over previous
//
#include <hip/hip_runtime.h>

#define MDIM 2048   // B
#define KD   2560   // HEAD
#define NHID 2048   // N_HID
#define INF  512
#define NS   40     // K-steps of 64

typedef __attribute__((ext_vector_type(16))) float f32x16;
typedef __attribute__((ext_vector_type(8))) short short8;
typedef __attribute__((ext_vector_type(8))) unsigned short ushort8v;
typedef __attribute__((ext_vector_type(4))) unsigned short ushort4v;

#define AS1 __attribute__((address_space(1)))
#define AS3 __attribute__((address_space(3)))

__device__ __forceinline__ unsigned short f2bf(float f) {
    unsigned u = __float_as_uint(f);
    u += 0x7fffu + ((u >> 16) & 1u);
    return (unsigned short)(u >> 16);
}
__device__ __forceinline__ float bf2f(unsigned short s) {
    return __uint_as_float(((unsigned)s) << 16);
}

// ---------------- prep: xc = concat(x, hidden) -> bf16 [MDIM][KD] ----------------
__global__ void prep_xc(const float* __restrict__ x, const float* __restrict__ h,
                        unsigned short* __restrict__ xc) {
    int idx = blockIdx.x * 256 + threadIdx.x;
    int e = idx * 8;
    int b = e / KD;
    int c = e - b * KD;
    const float* src = (c < INF) ? (x + (size_t)b * INF + c)
                                 : (h + (size_t)b * NHID + (c - INF));
    float4 v0 = *(const float4*)src;
    float4 v1 = *(const float4*)(src + 4);
    ushort8v o;
    o[0] = f2bf(v0.x); o[1] = f2bf(v0.y); o[2] = f2bf(v0.z); o[3] = f2bf(v0.w);
    o[4] = f2bf(v1.x); o[5] = f2bf(v1.y); o[6] = f2bf(v1.z); o[7] = f2bf(v1.w);
    *(ushort8v*)(xc + e) = o;
}

// ---------------- prep: Wm[k] = W_k * mask -> bf16, 5 planes [5*NHID][KD] ----------------
__global__ void prep_wm(const float* __restrict__ Wg, const float* __restrict__ Wh,
                        const float* __restrict__ Wfg, const float* __restrict__ Wfh,
                        const float* __restrict__ Wp, const float* __restrict__ mask,
                        unsigned short* __restrict__ Wm) {
    int idx = blockIdx.x * 256 + threadIdx.x;
    size_t e = (size_t)idx * 4;
    const size_t PL = (size_t)NHID * KD;
    int col = (int)(e % KD);
    float4 m;
    if (col < INF) m = *(const float4*)(mask + e);
    else           m = make_float4(1.f, 1.f, 1.f, 1.f);
    const float* Ws[5] = {Wg, Wh, Wfg, Wfh, Wp};
    #pragma unroll
    for (int k = 0; k < 5; ++k) {
        float4 w = *(const float4*)(Ws[k] + e);
        ushort4v o;
        o[0] = f2bf(w.x * m.x); o[1] = f2bf(w.y * m.y);
        o[2] = f2bf(w.z * m.z); o[3] = f2bf(w.w * m.w);
        *(ushort4v*)(Wm + k * PL + e) = o;
    }
}

// ---------------- fused GEMM + epilogue ----------------
// Block tile: 256 rows x 64 cols x 5 planes. B-tile = 5x64 = 320 Wm rows (LDS
// row R = plane*64 + r <-> global row plane*NHID + n0c + r). 8 waves (4M x 2N,
// 2 waves/SIMD for TLP), 32x32x16 MFMA, per-wave acc[2][5] (m-frags x planes).
// Single barrier per K-tile, free compiler schedule (fine-grained lgkmcnt
// pipelining + 2-wave TLP hides LDS under MFMA). Swizzle key (row^row>>3)&7
// spreads each 8-lane read group across all 32 banks (round-4 key row&7 left
// 4 lanes on identical banks -> 9.2e6 conflict cycles).
// Epilogue in-register: all 5 plane values per (row,col) live in acc ->
// tanh/sigmoid/mix -> direct f32 stores. No C buffer, no epilogue kernel.
#define MFMA32(d, va, vb) d = __builtin_amdgcn_mfma_f32_32x32x16_bf16(va, vb, d, 0, 0, 0)

__global__ __launch_bounds__(512, 2) void gemm_fused(
    const unsigned short* __restrict__ A,
    const unsigned short* __restrict__ Bm,
    const float* __restrict__ bg, const float* __restrict__ bh,
    const float* __restrict__ bfg, const float* __restrict__ bfh,
    const float* __restrict__ bp,
    float* __restrict__ out) {
    __shared__ unsigned short lsA[2][256 * 64];   // 64 KB
    __shared__ unsigned short lsB[2][320 * 64];   // 80 KB

    const int tid  = threadIdx.x;
    const int lane = tid & 63;
    const int w    = tid >> 6;       // 0..7
    const int wm   = w >> 1;         // 0..3  (M waves)
    const int wn   = w & 1;          // 0..1  (N col-half)
    const int l31  = lane & 31;
    const int hi   = lane >> 5;      // 0..1
    const int l7   = lane & 7;
    const int u    = l31 >> 3;       // 0..3 (read-row subgroup)
    const int su   = lane >> 3;      // 0..7 (staging row-in-group)
    const int sc   = lane & 7;       // staging slot
    const int m0   = blockIdx.y * 256;
    const int n0c  = blockIdx.x * 64;

    const unsigned short* gA = A + (size_t)m0 * KD;
    const int ar0 = (w >> 2) * 128 + (w & 3) * 8;   // + 32*j, j=0..3  (A rows)
    const int br0 = (w >> 1) * 80 + (w & 1) * 8;    // + 16*j, j=0..4  (B LDS rows)

    // staging: LDS[R][slot] = G[grow(R)][slot ^ key(R)], key(R)=(R^(R>>3))&7.
    // lane writes LDS row r0+su, slot sc  ->  source col slot sc^su^((r0>>3)&7)
#define SA(j, t, b) do { \
        const int r0 = ar0 + 32 * (j); \
        const int colv = ((sc ^ su ^ ((r0 >> 3) & 7)) << 3) + (t) * 64; \
        __builtin_amdgcn_global_load_lds( \
            (const AS1 unsigned int*)(gA + (size_t)(r0 + su) * KD + colv), \
            (AS3 unsigned int*)(&lsA[b][r0 * 64]), 16, 0, 0); \
    } while (0)
#define SB(j, t, b) do { \
        const int r0 = br0 + 16 * (j); \
        const int grow = (r0 >> 6) * NHID + n0c + (r0 & 63); \
        const int colv = ((sc ^ su ^ ((r0 >> 3) & 7)) << 3) + (t) * 64; \
        __builtin_amdgcn_global_load_lds( \
            (const AS1 unsigned int*)(Bm + (size_t)(grow + su) * KD + colv), \
            (AS3 unsigned int*)(&lsB[b][r0 * 64]), 16, 0, 0); \
    } while (0)
#define STAGE(t, b) do { \
        SA(0, t, b); SA(1, t, b); SA(2, t, b); SA(3, t, b); \
        SB(0, t, b); SB(1, t, b); SB(2, t, b); SB(3, t, b); SB(4, t, b); \
    } while (0)

    // fragment read rows
    const int arow = wm * 64 + l31;    // + 32*m, m=0..1
    const int brow = wn * 32 + l31;    // + 64*p (plane-major LDS)
    // read swizzle keys: slot = (2s+hi) ^ l7 ^ ((row>>3)&7)
    const int keyB = ((4 * wn + u) & 7);

    f32x16 acc[2][5] = {};

    STAGE(0, 0);
    asm volatile("s_waitcnt vmcnt(0)" ::: "memory");
    __builtin_amdgcn_s_barrier();

    for (int kt = 0; kt < NS; ++kt) {
        const int bc = kt & 1, bo = bc ^ 1;
        if (kt < NS - 1) STAGE(kt + 1, bo);
        #pragma unroll
        for (int s = 0; s < 4; ++s) {
            const int g = 2 * s + hi;
            short8 av[2], bv[5];
            #pragma unroll
            for (int m = 0; m < 2; ++m) {
                const int cs = ((g ^ l7 ^ ((4 * m + u) & 7)) << 3);
                av[m] = *(const short8*)&lsA[bc][(arow + 32 * m) * 64 + cs];
            }
            {
                const int cs = ((g ^ l7 ^ keyB) << 3);
                #pragma unroll
                for (int p = 0; p < 5; ++p)
                    bv[p] = *(const short8*)&lsB[bc][(brow + 64 * p) * 64 + cs];
            }
            __builtin_amdgcn_s_setprio(1);
            #pragma unroll
            for (int m = 0; m < 2; ++m)
                #pragma unroll
                for (int p = 0; p < 5; ++p)
                    MFMA32(acc[m][p], av[m], bv[p]);
            __builtin_amdgcn_s_setprio(0);
        }
        asm volatile("s_waitcnt vmcnt(0)" ::: "memory");
        __builtin_amdgcn_s_barrier();
    }

    // ---- fused epilogue ----
    // C/D layout (32x32): col = lane&31, row = (reg&3) + 8*(reg>>2) + 4*hi
    const int col = n0c + wn * 32 + l31;
    const float bgv  = bg[col];
    const float bhv  = bh[col];
    const float bfv  = bfg[col] + bfh[col];
    const float bpv  = bp[col];
    const size_t PL = (size_t)MDIM * NHID;
    #pragma unroll
    for (int m = 0; m < 2; ++m) {
        #pragma unroll
        for (int q = 0; q < 4; ++q) {
            #pragma unroll
            for (int t = 0; t < 4; ++t) {
                const int e = q * 4 + t;
                const int row = m0 + wm * 64 + m * 32 + q * 8 + 4 * hi + t;
                float gx = acc[m][0][e] + bgv;
                float hx = acc[m][1][e] + bhv;
                float sx = acc[m][2][e] + acc[m][3][e] + bfv;
                // tanh via exp(-2|x|), safe for all x
                float tg = __expf(-2.0f * fabsf(gx));
                float g  = __builtin_copysignf((1.0f - tg) / (1.0f + tg), gx);
                float th = __expf(-2.0f * fabsf(hx));
                float hh = __builtin_copysignf((1.0f - th) / (1.0f + th), hx);
                float gate = 1.0f / (1.0f + __expf(-sx));
                float nh = g * (1.0f - gate) + gate * hh;
                float y  = acc[m][4][e] + bpv + nh;
                out[(size_t)row * NHID + col]      = y;
                out[PL + (size_t)row * NHID + col] = nh;
            }
        }
    }
#undef SA
#undef SB
#undef STAGE
}

extern "C" void kernel_launch(void* const* d_in, const int* in_sizes, int n_in,
                              void* d_out, int out_size, void* d_ws, size_t ws_size,
                              hipStream_t stream) {
    const float* x      = (const float*)d_in[0];
    const float* hidden = (const float*)d_in[1];
    const float* mask   = (const float*)d_in[2];
    const float* Wg     = (const float*)d_in[3];
    const float* bg     = (const float*)d_in[4];
    const float* Wh     = (const float*)d_in[5];
    const float* bh     = (const float*)d_in[6];
    const float* Wfg    = (const float*)d_in[7];
    const float* bfg    = (const float*)d_in[8];
    const float* Wfh    = (const float*)d_in[9];
    const float* bfh    = (const float*)d_in[10];
    const float* Wp     = (const float*)d_in[11];
    const float* bp     = (const float*)d_in[12];
    float* out = (float*)d_out;

    const size_t need = (size_t)MDIM * KD * 2 + (size_t)5 * NHID * KD * 2;
    if (ws_size < need) return;

    unsigned short* xc = (unsigned short*)d_ws;
    unsigned short* Wm = xc + (size_t)MDIM * KD;

    prep_xc<<<MDIM * KD / 8 / 256, 256, 0, stream>>>(x, hidden, xc);
    prep_wm<<<NHID * KD / 4 / 256, 256, 0, stream>>>(Wg, Wh, Wfg, Wfh, Wp, mask, Wm);
    dim3 grid(NHID / 64, MDIM / 256);
    gemm_fused<<<grid, 512, 0, stream>>>(xc, Wm, bg, bh, bfg, bfh, bp, out);
}

// Round 8
// 138.248 us; speedup vs baseline: 3.7067x; 1.0063x over previous
//
#include <hip/hip_runtime.h>

#define MDIM 2048   // B
#define KD   2560   // HEAD
#define NHID 2048   // N_HID
#define INF  512
#define NS   40     // K-steps of 64

typedef __attribute__((ext_vector_type(16))) float f32x16;
typedef __attribute__((ext_vector_type(8))) short short8;
typedef __attribute__((ext_vector_type(8))) unsigned short ushort8v;
typedef __attribute__((ext_vector_type(4))) unsigned short ushort4v;

#define AS1 __attribute__((address_space(1)))
#define AS3 __attribute__((address_space(3)))

__device__ __forceinline__ unsigned short f2bf(float f) {
    unsigned u = __float_as_uint(f);
    u += 0x7fffu + ((u >> 16) & 1u);
    return (unsigned short)(u >> 16);
}
__device__ __forceinline__ float bf2f(unsigned short s) {
    return __uint_as_float(((unsigned)s) << 16);
}

// ---------------- prep: xc = concat(x, hidden) -> bf16 [MDIM][KD] ----------------
__global__ void prep_xc(const float* __restrict__ x, const float* __restrict__ h,
                        unsigned short* __restrict__ xc) {
    int idx = blockIdx.x * 256 + threadIdx.x;
    int e = idx * 8;
    int b = e / KD;
    int c = e - b * KD;
    const float* src = (c < INF) ? (x + (size_t)b * INF + c)
                                 : (h + (size_t)b * NHID + (c - INF));
    float4 v0 = *(const float4*)src;
    float4 v1 = *(const float4*)(src + 4);
    ushort8v o;
    o[0] = f2bf(v0.x); o[1] = f2bf(v0.y); o[2] = f2bf(v0.z); o[3] = f2bf(v0.w);
    o[4] = f2bf(v1.x); o[5] = f2bf(v1.y); o[6] = f2bf(v1.z); o[7] = f2bf(v1.w);
    *(ushort8v*)(xc + e) = o;
}

// ---------------- prep: Wm[k] = W_k * mask -> bf16, 5 planes [5*NHID][KD] ----------------
__global__ void prep_wm(const float* __restrict__ Wg, const float* __restrict__ Wh,
                        const float* __restrict__ Wfg, const float* __restrict__ Wfh,
                        const float* __restrict__ Wp, const float* __restrict__ mask,
                        unsigned short* __restrict__ Wm) {
    int idx = blockIdx.x * 256 + threadIdx.x;
    size_t e = (size_t)idx * 4;
    const size_t PL = (size_t)NHID * KD;
    int col = (int)(e % KD);
    float4 m;
    if (col < INF) m = *(const float4*)(mask + e);
    else           m = make_float4(1.f, 1.f, 1.f, 1.f);
    const float* Ws[5] = {Wg, Wh, Wfg, Wfh, Wp};
    #pragma unroll
    for (int k = 0; k < 5; ++k) {
        float4 w = *(const float4*)(Ws[k] + e);
        ushort4v o;
        o[0] = f2bf(w.x * m.x); o[1] = f2bf(w.y * m.y);
        o[2] = f2bf(w.z * m.z); o[3] = f2bf(w.w * m.w);
        *(ushort4v*)(Wm + k * PL + e) = o;
    }
}

// ---------------- fused GEMM + epilogue ----------------
// Round-7 structure (256x64x5 tile, 8 waves 4Mx2N, 32x32x16, fused epilogue)
// + two changes per the serial-LDS+MFMA cycle model:
//   1. explicit 1-deep fragment prefetch (reads(s+1) issued before MFMA(s),
//      double-buffered frag regs, static idx) -> LDS streams under MFMA.
//   2. ds_read byte-offsets (28) precomputed per-lane before the loop ->
//      kills per-iteration swizzle-address VALU (~1100 cyc/K-tile).
#define MFMA32(d, va, vb) d = __builtin_amdgcn_mfma_f32_32x32x16_bf16(va, vb, d, 0, 0, 0)

__global__ __launch_bounds__(512, 2) void gemm_fused(
    const unsigned short* __restrict__ A,
    const unsigned short* __restrict__ Bm,
    const float* __restrict__ bg, const float* __restrict__ bh,
    const float* __restrict__ bfg, const float* __restrict__ bfh,
    const float* __restrict__ bp,
    float* __restrict__ out) {
    __shared__ unsigned short lsA[2][256 * 64];   // 64 KB
    __shared__ unsigned short lsB[2][320 * 64];   // 80 KB

    const int tid  = threadIdx.x;
    const int lane = tid & 63;
    const int w    = tid >> 6;       // 0..7
    const int wm   = w >> 1;         // 0..3  (M waves)
    const int wn   = w & 1;          // 0..1  (N col-half)
    const int l31  = lane & 31;
    const int hi   = lane >> 5;      // 0..1
    const int l7   = lane & 7;
    const int u    = l31 >> 3;       // 0..3 (read-row subgroup)
    const int su   = lane >> 3;      // 0..7 (staging row-in-group)
    const int sc   = lane & 7;       // staging slot
    const int m0   = blockIdx.y * 256;
    const int n0c  = blockIdx.x * 64;

    const unsigned short* gA = A + (size_t)m0 * KD;
    const int ar0 = (w >> 2) * 128 + (w & 3) * 8;   // + 32*j, j=0..3  (A rows)
    const int br0 = (w >> 1) * 80 + (w & 1) * 8;    // + 16*j, j=0..4  (B LDS rows)

    // staging: LDS[R][slot] = G[grow(R)][slot ^ key(R)], key(R)=(R^(R>>3))&7.
#define SA(j, t, b) do { \
        const int r0 = ar0 + 32 * (j); \
        const int colv = ((sc ^ su ^ ((r0 >> 3) & 7)) << 3) + (t) * 64; \
        __builtin_amdgcn_global_load_lds( \
            (const AS1 unsigned int*)(gA + (size_t)(r0 + su) * KD + colv), \
            (AS3 unsigned int*)(&lsA[b][r0 * 64]), 16, 0, 0); \
    } while (0)
#define SB(j, t, b) do { \
        const int r0 = br0 + 16 * (j); \
        const int grow = (r0 >> 6) * NHID + n0c + (r0 & 63); \
        const int colv = ((sc ^ su ^ ((r0 >> 3) & 7)) << 3) + (t) * 64; \
        __builtin_amdgcn_global_load_lds( \
            (const AS1 unsigned int*)(Bm + (size_t)(grow + su) * KD + colv), \
            (AS3 unsigned int*)(&lsB[b][r0 * 64]), 16, 0, 0); \
    } while (0)
#define STAGE(t, b) do { \
        SA(0, t, b); SA(1, t, b); SA(2, t, b); SA(3, t, b); \
        SB(0, t, b); SB(1, t, b); SB(2, t, b); SB(3, t, b); SB(4, t, b); \
    } while (0)

    // fragment read rows + loop-invariant per-lane byte offsets
    const int arow = wm * 64 + l31;    // + 32*m
    const int brow = wn * 32 + l31;    // + 64*p (plane-major LDS)
    const int keyB = ((4 * wn + u) & 7);

    int offA[2][4], offB[5][4];
    #pragma unroll
    for (int m = 0; m < 2; ++m)
        #pragma unroll
        for (int s = 0; s < 4; ++s)
            offA[m][s] = (arow + 32 * m) * 128
                       + ((((2 * s + hi) ^ l7 ^ ((4 * m + u) & 7))) << 4);
    #pragma unroll
    for (int p = 0; p < 5; ++p)
        #pragma unroll
        for (int s = 0; s < 4; ++s)
            offB[p][s] = (brow + 64 * p) * 128
                       + ((((2 * s + hi) ^ l7 ^ keyB)) << 4);

    f32x16 acc[2][5] = {};

    STAGE(0, 0);
    asm volatile("s_waitcnt vmcnt(0)" ::: "memory");
    __builtin_amdgcn_s_barrier();

    for (int kt = 0; kt < NS; ++kt) {
        const int bc = kt & 1, bo = bc ^ 1;
        const char* baseA = (const char*)&lsA[bc][0];
        const char* baseB = (const char*)&lsB[bc][0];
        if (kt < NS - 1) STAGE(kt + 1, bo);

        short8 av[2][2], bv[2][5];
        // prime s=0
        #pragma unroll
        for (int m = 0; m < 2; ++m) av[0][m] = *(const short8*)(baseA + offA[m][0]);
        #pragma unroll
        for (int p = 0; p < 5; ++p) bv[0][p] = *(const short8*)(baseB + offB[p][0]);

        #pragma unroll
        for (int s = 0; s < 4; ++s) {
            const int cur = s & 1, nxt = cur ^ 1;
            if (s < 3) {   // issue reads(s+1) BEFORE MFMA(s): counted lgkm wait
                #pragma unroll
                for (int m = 0; m < 2; ++m)
                    av[nxt][m] = *(const short8*)(baseA + offA[m][s + 1]);
                #pragma unroll
                for (int p = 0; p < 5; ++p)
                    bv[nxt][p] = *(const short8*)(baseB + offB[p][s + 1]);
            }
            __builtin_amdgcn_s_setprio(1);
            #pragma unroll
            for (int m = 0; m < 2; ++m)
                #pragma unroll
                for (int p = 0; p < 5; ++p)
                    MFMA32(acc[m][p], av[cur][m], bv[cur][p]);
            __builtin_amdgcn_s_setprio(0);
        }
        asm volatile("s_waitcnt vmcnt(0)" ::: "memory");
        __builtin_amdgcn_s_barrier();
    }

    // ---- fused epilogue ----
    // C/D layout (32x32): col = lane&31, row = (reg&3) + 8*(reg>>2) + 4*hi
    const int col = n0c + wn * 32 + l31;
    const float bgv  = bg[col];
    const float bhv  = bh[col];
    const float bfv  = bfg[col] + bfh[col];
    const float bpv  = bp[col];
    const size_t PL = (size_t)MDIM * NHID;
    #pragma unroll
    for (int m = 0; m < 2; ++m) {
        #pragma unroll
        for (int q = 0; q < 4; ++q) {
            #pragma unroll
            for (int t = 0; t < 4; ++t) {
                const int e = q * 4 + t;
                const int row = m0 + wm * 64 + m * 32 + q * 8 + 4 * hi + t;
                float gx = acc[m][0][e] + bgv;
                float hx = acc[m][1][e] + bhv;
                float sx = acc[m][2][e] + acc[m][3][e] + bfv;
                float tg = __expf(-2.0f * fabsf(gx));
                float g  = __builtin_copysignf((1.0f - tg) / (1.0f + tg), gx);
                float th = __expf(-2.0f * fabsf(hx));
                float hh = __builtin_copysignf((1.0f - th) / (1.0f + th), hx);
                float gate = 1.0f / (1.0f + __expf(-sx));
                float nh = g * (1.0f - gate) + gate * hh;
                float y  = acc[m][4][e] + bpv + nh;
                out[(size_t)row * NHID + col]      = y;
                out[PL + (size_t)row * NHID + col] = nh;
            }
        }
    }
#undef SA
#undef SB
#undef STAGE
}

extern "C" void kernel_launch(void* const* d_in, const int* in_sizes, int n_in,
                              void* d_out, int out_size, void* d_ws, size_t ws_size,
                              hipStream_t stream) {
    const float* x      = (const float*)d_in[0];
    const float* hidden = (const float*)d_in[1];
    const float* mask   = (const float*)d_in[2];
    const float* Wg     = (const float*)d_in[3];
    const float* bg     = (const float*)d_in[4];
    const float* Wh     = (const float*)d_in[5];
    const float* bh     = (const float*)d_in[6];
    const float* Wfg    = (const float*)d_in[7];
    const float* bfg    = (const float*)d_in[8];
    const float* Wfh    = (const float*)d_in[9];
    const float* bfh    = (const float*)d_in[10];
    const float* Wp     = (const float*)d_in[11];
    const float* bp     = (const float*)d_in[12];
    float* out = (float*)d_out;

    const size_t need = (size_t)MDIM * KD * 2 + (size_t)5 * NHID * KD * 2;
    if (ws_size < need) return;

    unsigned short* xc = (unsigned short*)d_ws;
    unsigned short* Wm = xc + (size_t)MDIM * KD;

    prep_xc<<<MDIM * KD / 8 / 256, 256, 0, stream>>>(x, hidden, xc);
    prep_wm<<<NHID * KD / 4 / 256, 256, 0, stream>>>(Wg, Wh, Wfg, Wfh, Wp, mask, Wm);
    dim3 grid(NHID / 64, MDIM / 256);
    gemm_fused<<<grid, 512, 0, stream>>>(xc, Wm, bg, bh, bfg, bfh, bp, out);
}